// Round 11
// baseline (211.305 us; speedup 1.0000x reference)
//
#include <hip/hip_runtime.h>
#include <math.h>

#define B_   4
#define T_   512
#define TAU_ 512
#define L_   1024
#define DM_  1024
#define H_   16
#define D_   64

typedef short  s16x8 __attribute__((ext_vector_type(8)));   // 8 bf16 MFMA frag
typedef ushort u16x4 __attribute__((ext_vector_type(4)));
typedef float  f32x4 __attribute__((ext_vector_type(4)));

#define SC_LOG2 0.18033688011f   // 0.125 * log2(e): softmax runs in exp2 domain

__device__ __forceinline__ ushort f2bf(float x) {   // RNE float->bf16 bits
  uint u = __float_as_uint(x);
  u += 0x7fffu + ((u >> 16) & 1u);
  return (ushort)(u >> 16);
}
__device__ __forceinline__ float bf2f(ushort u) {
  return __uint_as_float(((uint)u) << 16);
}
// XOR-swizzle for bf16 [rows][64] LDS tiles (128B rows): permute 16B slots by row&7
__device__ __forceinline__ int sw64(int row, int col) {
  return row * 64 + (col ^ ((row & 7) << 3));
}

// ---------------------------------------------------------------------------
// Fused preprocessing, launch-overhead-minimized (3328 blocks):
// [0,1024)    LayerNorm: one WAVE per row (4 rows/block, no barriers)
// [1024,2048) phi table: 4 elems/thread
// [2048,3328) weight fp32->bf16 casts: 4 float4/thread
// ---------------------------------------------------------------------------
__global__ __launch_bounds__(256) void prep_kernel(
    const float* __restrict__ inp, const float* __restrict__ mem,
    const float* __restrict__ gamma, const float* __restrict__ beta,
    ushort* __restrict__ xn, ushort* __restrict__ phi,
    const float* __restrict__ wq, ushort* __restrict__ wqb,
    const float* __restrict__ wp, ushort* __restrict__ wpb,
    const float* __restrict__ wo, ushort* __restrict__ wob) {
  int blk = blockIdx.x;
  int t = threadIdx.x;
  if (blk < 1024) {                    // ---- LayerNorm, wave per row ----
    int wid = t >> 6, lane = t & 63;
    int row = blk * 4 + wid;           // b*L + l
    int b = row >> 10, l = row & 1023;
    const float* src = (l < TAU_)
        ? mem + ((size_t)b * TAU_ + l) * DM_
        : inp + ((size_t)b * T_ + (l - TAU_)) * DM_;
    float4 v[4];
    float s1 = 0.f, s2 = 0.f;
#pragma unroll
    for (int c = 0; c < 4; ++c) {
      v[c] = *(const float4*)(src + c * 256 + lane * 4);
      s1 += v[c].x + v[c].y + v[c].z + v[c].w;
      s2 += v[c].x * v[c].x + v[c].y * v[c].y + v[c].z * v[c].z + v[c].w * v[c].w;
    }
#pragma unroll
    for (int off = 32; off > 0; off >>= 1) {
      s1 += __shfl_xor(s1, off);
      s2 += __shfl_xor(s2, off);
    }
    float mu   = s1 * (1.0f / DM_);
    float var  = s2 * (1.0f / DM_) - mu * mu;
    float rstd = 1.0f / sqrtf(var + 1e-5f);
#pragma unroll
    for (int c = 0; c < 4; ++c) {
      float4 g  = *(const float4*)(gamma + c * 256 + lane * 4);
      float4 be = *(const float4*)(beta  + c * 256 + lane * 4);
      u16x4 o;
      o[0] = f2bf((v[c].x - mu) * rstd * g.x + be.x);
      o[1] = f2bf((v[c].y - mu) * rstd * g.y + be.y);
      o[2] = f2bf((v[c].z - mu) * rstd * g.z + be.z);
      o[3] = f2bf((v[c].w - mu) * rstd * g.w + be.w);
      *(u16x4*)(xn + (size_t)row * DM_ + c * 256 + lane * 4) = o;
    }
  } else if (blk < 2048) {             // ---- phi ----
    int base = (blk - 1024) * 1024 + t;
#pragma unroll
    for (int it = 0; it < 4; ++it) {
      int idx = base + it * 256;       // 0 .. 1M-1
      int m = idx >> 10, c = idx & 1023;
      float p = (float)(1023 - m);
      int cc = (c < 512) ? c : c - 512;
      float invf = __expf(-((float)(2 * cc) * (1.0f / 1024.0f)) * 9.210340371976184f);
      float a = p * invf;
      phi[idx] = f2bf((c < 512) ? __sinf(a) : __cosf(a));
    }
  } else {                             // ---- weight casts ----
    int base = (blk - 2048) * 1024 + t;   // float4-group index
#pragma unroll
    for (int it = 0; it < 4; ++it) {
      int i = base + it * 256;            // < 1310720 exactly
      const float* src; ushort* dst; int off;
      if (i < 786432)       { src = wq; dst = wqb; off = i; }
      else if (i < 1048576) { src = wp; dst = wpb; off = i - 786432; }
      else                  { src = wo; dst = wob; off = i - 1048576; }
      float4 v = *(const float4*)(src + (size_t)off * 4);
      u16x4 o = { f2bf(v.x), f2bf(v.y), f2bf(v.z), f2bf(v.w) };
      *(u16x4*)(dst + (size_t)off * 4) = o;
    }
  }
}

// ---------------------------------------------------------------------------
// bf16 MFMA NT GEMM body: m97 structure, 128x128 tile, BK=64 (round-8 exact).
// ---------------------------------------------------------------------------
template <typename CT>
__device__ __forceinline__ void gemm_nt_body(
    const ushort* __restrict__ A, const ushort* __restrict__ B,
    CT* __restrict__ C, int M, int N, int K, int bx, int by) {
  __shared__ __attribute__((aligned(16))) ushort As[128 * 64];
  __shared__ __attribute__((aligned(16))) ushort Bs[128 * 64];
  int t = threadIdx.x;
  int w = t >> 6, lane = t & 63, g = lane >> 4, low = lane & 15;
  int wr = w >> 1, wc = w & 1;               // wave 2x2 grid, 64x64 each
  int m0 = by * 128, n0 = bx * 128;
  f32x4 acc[4][4] = {};

  for (int kt = 0; kt < K; kt += 64) {
    __syncthreads();                         // prev-iter LDS reads done
#pragma unroll
    for (int q = 0; q < 4; ++q) {
      int c = t + q * 256;                   // 16B chunk id 0..1023
      int row = c >> 3;
      int gslot = (c & 7) ^ (row & 7);       // inverse swizzle on source
      const ushort* ga = A + (size_t)(m0 + row) * K + kt + gslot * 8;
      const ushort* gb = B + (size_t)(n0 + row) * K + kt + gslot * 8;
      __builtin_amdgcn_global_load_lds(
          (const __attribute__((address_space(1))) void*)ga,
          (__attribute__((address_space(3))) void*)&As[(q * 256 + w * 64) * 8],
          16, 0, 0);
      __builtin_amdgcn_global_load_lds(
          (const __attribute__((address_space(1))) void*)gb,
          (__attribute__((address_space(3))) void*)&Bs[(q * 256 + w * 64) * 8],
          16, 0, 0);
    }
    __syncthreads();                         // vmcnt(0) drain: tiles ready

#pragma unroll
    for (int kc = 0; kc < 2; ++kc) {
      s16x8 af[4], bfr[4];
#pragma unroll
      for (int mi = 0; mi < 4; ++mi) {
        int row = wr * 64 + mi * 16 + low;
        af[mi] = *(const s16x8*)&As[row * 64 + (((4 * kc + g) ^ (row & 7)) * 8)];
      }
#pragma unroll
      for (int ni = 0; ni < 4; ++ni) {
        int col = wc * 64 + ni * 16 + low;
        bfr[ni] = *(const s16x8*)&Bs[col * 64 + (((4 * kc + g) ^ (col & 7)) * 8)];
      }
#pragma unroll
      for (int mi = 0; mi < 4; ++mi)
#pragma unroll
        for (int ni = 0; ni < 4; ++ni)
          acc[mi][ni] = __builtin_amdgcn_mfma_f32_16x16x32_bf16(
              af[mi], bfr[ni], acc[mi][ni], 0, 0, 0);
    }
  }
#pragma unroll
  for (int mi = 0; mi < 4; ++mi)
#pragma unroll
    for (int ni = 0; ni < 4; ++ni)
#pragma unroll
      for (int r = 0; r < 4; ++r) {
        int m = m0 + wr * 64 + mi * 16 + 4 * g + r;
        int n = n0 + wc * 64 + ni * 16 + low;
        if constexpr (sizeof(CT) == 2)
          C[(size_t)m * N + n] = f2bf(acc[mi][ni][r]);
        else
          C[(size_t)m * N + n] = acc[mi][ni][r];
      }
}

// ---------------------------------------------------------------------------
// BN=64 variant (128x64 tile), BK=64. LDS 24KB.
// ---------------------------------------------------------------------------
template <typename CT>
__device__ __forceinline__ void gemm_nt_body_n64(
    const ushort* __restrict__ A, const ushort* __restrict__ B,
    CT* __restrict__ C, int M, int N, int K, int bx, int by) {
  __shared__ __attribute__((aligned(16))) ushort As[128 * 64];
  __shared__ __attribute__((aligned(16))) ushort Bs[64 * 64];
  int t = threadIdx.x;
  int w = t >> 6, lane = t & 63, g = lane >> 4, low = lane & 15;
  int wr = w >> 1, wc = w & 1;               // each wave: 64 rows x 32 cols
  int m0 = by * 128, n0 = bx * 64;
  f32x4 acc[4][2] = {};

  for (int kt = 0; kt < K; kt += 64) {
    __syncthreads();
#pragma unroll
    for (int q = 0; q < 4; ++q) {            // A: 1024 chunks
      int c = t + q * 256;
      int row = c >> 3;
      int gslot = (c & 7) ^ (row & 7);
      const ushort* ga = A + (size_t)(m0 + row) * K + kt + gslot * 8;
      __builtin_amdgcn_global_load_lds(
          (const __attribute__((address_space(1))) void*)ga,
          (__attribute__((address_space(3))) void*)&As[(q * 256 + w * 64) * 8],
          16, 0, 0);
    }
#pragma unroll
    for (int q = 0; q < 2; ++q) {            // B: 512 chunks
      int c = t + q * 256;
      int row = c >> 3;
      int gslot = (c & 7) ^ (row & 7);
      const ushort* gb = B + (size_t)(n0 + row) * K + kt + gslot * 8;
      __builtin_amdgcn_global_load_lds(
          (const __attribute__((address_space(1))) void*)gb,
          (__attribute__((address_space(3))) void*)&Bs[(q * 256 + w * 64) * 8],
          16, 0, 0);
    }
    __syncthreads();

#pragma unroll
    for (int kc = 0; kc < 2; ++kc) {
      s16x8 af[4], bfr[2];
#pragma unroll
      for (int mi = 0; mi < 4; ++mi) {
        int row = wr * 64 + mi * 16 + low;
        af[mi] = *(const s16x8*)&As[row * 64 + (((4 * kc + g) ^ (row & 7)) * 8)];
      }
#pragma unroll
      for (int ni = 0; ni < 2; ++ni) {
        int col = wc * 32 + ni * 16 + low;
        bfr[ni] = *(const s16x8*)&Bs[col * 64 + (((4 * kc + g) ^ (col & 7)) * 8)];
      }
#pragma unroll
      for (int mi = 0; mi < 4; ++mi)
#pragma unroll
        for (int ni = 0; ni < 2; ++ni)
          acc[mi][ni] = __builtin_amdgcn_mfma_f32_16x16x32_bf16(
              af[mi], bfr[ni], acc[mi][ni], 0, 0, 0);
    }
  }
#pragma unroll
  for (int mi = 0; mi < 4; ++mi)
#pragma unroll
    for (int ni = 0; ni < 2; ++ni)
#pragma unroll
      for (int r = 0; r < 4; ++r) {
        int m = m0 + wr * 64 + mi * 16 + 4 * g + r;
        int n = n0 + wc * 32 + ni * 16 + low;
        if constexpr (sizeof(CT) == 2)
          C[(size_t)m * N + n] = f2bf(acc[mi][ni][r]);
        else
          C[(size_t)m * N + n] = acc[mi][ni][r];
      }
}

// QKV GEMM (768 tiles) + R GEMM (64 tiles) in one 832-block dispatch.
// Bijective XCD swizzle (832 = 8 x 104).
__global__ __launch_bounds__(256) void qkv_r_gemm(
    const ushort* __restrict__ xnb, const ushort* __restrict__ wqb,
    ushort* __restrict__ qkvB,
    const ushort* __restrict__ phib, const ushort* __restrict__ wpb,
    ushort* __restrict__ RmB) {
  int orig = blockIdx.x;
  int id = (orig & 7) * 104 + (orig >> 3);
  if (id < 768)
    gemm_nt_body<ushort>(xnb, wqb, qkvB, 4096, 3072, 1024, id % 24, id / 24);
  else {
    id -= 768;
    gemm_nt_body<ushort>(phib, wpb, RmB, 1024, 1024, 1024, id % 8, id / 8);
  }
}

// out GEMM with 128x64 tiles: 256 blocks = 1/CU.
__global__ __launch_bounds__(256) void out_gemm(
    const ushort* __restrict__ attnb, const ushort* __restrict__ wob,
    float* __restrict__ out) {
  int orig = blockIdx.x;                     // 256 = 8 x 32
  int id = (orig & 7) * 32 + (orig >> 3);
  gemm_nt_body_n64<float>(attnb, wob, out, 2048, 1024, 1024, id % 16, id / 16);
}

// ---------------------------------------------------------------------------
// MFMA bf16 flash attention with rel-shift (round-10 structure: XCD family
// swizzle + in-kernel V transpose + K/R DMA double-buffer).
// NEW (isolated trims): exp2-domain softmax, T13 defer-rescale (THR=8),
// wave-uniform mask skip.
// ---------------------------------------------------------------------------
__global__ __launch_bounds__(256) void attn_mfma_kernel(
    const ushort* __restrict__ qkv, const ushort* __restrict__ Rm,
    const float* __restrict__ uvar, const float* __restrict__ vvar,
    ushort* __restrict__ attn) {
  __shared__ __attribute__((aligned(16))) ushort Ks[2][64 * 64];
  __shared__ __attribute__((aligned(16))) ushort Vt[2][64 * 64];
  __shared__ __attribute__((aligned(16))) ushort Rs[2][128 * 64];
  __shared__ __attribute__((aligned(16))) ushort Pp[4][16 * 64];

  int t   = threadIdx.x;
  int w   = t >> 6;          // wave 0..3
  int lw  = t & 63;
  int g   = lw >> 4;         // k-group 0..3
  int low = lw & 15;

  int orig = blockIdx.x;     // XCD of a block = orig & 7 (round-robin model)
  int bid  = (orig & 7) * 64 + (orig >> 3);   // XCD owns 64 consecutive bids
  int s    = bid & 7;                         // bi-slot within (b,h) family
  int h    = (bid >> 3) & 15;
  int b    = bid >> 7;
  int bi   = (s & 1) ? (7 - (s >> 1)) : (s >> 1);  // pairs (0,7)(1,6)(2,5)(3,4)
  int i0   = bi * 64;
  int lb_w = 48 - 16 * w;    // wave's P m-window base within Rs

  auto stage_kr = [&](int buf, int tl) {
    int j0s = tl * 64;
#pragma unroll
    for (int q = 0; q < 2; ++q) {
      int c = t + q * 256;                  // 16B chunk id 0..511
      int row = c >> 3;
      int sl = (c & 7) ^ (row & 7);
      const ushort* srck = qkv + (size_t)(b * L_ + j0s + row) * 3072 +
                           1024 + h * 64 + sl * 8;
      __builtin_amdgcn_global_load_lds(
          (const __attribute__((address_space(1))) void*)srck,
          (__attribute__((address_space(3))) void*)&Ks[buf][(q * 256 + w * 64) * 8],
          16, 0, 0);
    }
    int mb = j0s + 448 - i0;
#pragma unroll
    for (int q = 0; q < 4; ++q) {
      int c = t + q * 256;                  // chunk 0..1023
      int row = c >> 3;                     // R row 0..127
      int m = mb + row; m = (m > 1023) ? 1023 : m;
      int sl = (c & 7) ^ (row & 7);
      const ushort* srcr = Rm + (size_t)m * 1024 + h * 64 + sl * 8;
      __builtin_amdgcn_global_load_lds(
          (const __attribute__((address_space(1))) void*)srcr,
          (__attribute__((address_space(3))) void*)&Rs[buf][(q * 256 + w * 64) * 8],
          16, 0, 0);
    }
  };

  // V staging: reg-load (issue early) ...
  int vj  = t & 63;                         // wave-local j column
  int vd0 = (t >> 6) * 8;                   // wave-uniform d base (0,8,16,24)
  float4 vreg[2];
  auto vload = [&](int tl) {
    const ushort* p = qkv + (size_t)(b * L_ + tl * 64 + vj) * 3072 + 2048 + h * 64;
    vreg[0] = *(const float4*)(p + vd0);
    vreg[1] = *(const float4*)(p + vd0 + 32);
  };
  // ... transpose-write late (d rows wave-uniform: 64 lanes x 2B = no conflict)
  auto vwrite = [&](int buf) {
#pragma unroll
    for (int it = 0; it < 2; ++it) {
      ushort vals[8];
      *(float4*)vals = vreg[it];
#pragma unroll
      for (int e = 0; e < 8; ++e) {
        int d = it * 32 + vd0 + e;
        Vt[buf][d * 64 + (vj ^ ((d & 7) << 3))] = vals[e];
      }
    }
  };

  // Q fragments (bf16 source + fp32 u/v), loaded once
  int iq = i0 + 16 * w + low;
  s16x8 qu[2], qv[2];
  {
    const ushort* qrow = qkv + (size_t)(b * L_ + TAU_ + iq) * 3072 + h * 64;
    const float* ur = uvar + h * 64;
    const float* vr = vvar + h * 64;
#pragma unroll
    for (int kc = 0; kc < 2; ++kc) {
      int dbase = kc * 32 + 8 * g;
#pragma unroll
      for (int e = 0; e < 8; ++e) {
        float q = bf2f(qrow[dbase + e]);
        qu[kc][e] = (short)f2bf(q + ur[dbase + e]);
        qv[kc][e] = (short)f2bf(q + vr[dbase + e]);
      }
    }
  }

  f32x4 O[4] = {};
  float mreg[4] = {-INFINITY, -INFINITY, -INFINITY, -INFINITY};
  float lreg[4] = {0.f, 0.f, 0.f, 0.f};

  int ntiles = 9 + bi;       // covers j <= TAU + i0 + 63 exactly
  stage_kr(0, 0);
  vload(0);
  vwrite(0);                 // compiler inserts vmcnt wait on vreg use
  __syncthreads();           // drains DMA + LDS writes: tile 0 ready
  int cur = 0;
  for (int tile = 0; tile < ntiles; ++tile) {
    int j0 = tile * 64;
    bool more = (tile + 1 < ntiles);
    if (more) { stage_kr(cur ^ 1, tile + 1); vload(tile + 1); }

    // ---- QK^T ----
    f32x4 s4[4] = {};
#pragma unroll
    for (int jt = 0; jt < 4; ++jt) {
#pragma unroll
      for (int kc = 0; kc < 2; ++kc) {
        s16x8 kb = *(const s16x8*)&Ks[cur][sw64(jt * 16 + low, kc * 32 + 8 * g)];
        s4[jt] = __builtin_amdgcn_mfma_f32_16x16x32_bf16(qu[kc], kb, s4[jt], 0, 0, 0);
      }
    }
    // ---- P = (q+v)·R over the wave's 80-col m-window ----
    f32x4 p[5] = {};
#pragma unroll
    for (int mt = 0; mt < 5; ++mt) {
#pragma unroll
      for (int kc = 0; kc < 2; ++kc) {
        s16x8 rb = *(const s16x8*)&Rs[cur][sw64(lb_w + mt * 16 + low, kc * 32 + 8 * g)];
        p[mt] = __builtin_amdgcn_mfma_f32_16x16x32_bf16(qv[kc], rb, p[mt], 0, 0, 0);
      }
    }
    // ---- rel-shift via shfl; scale (+mask only when needed) in exp2 domain ----
    bool fullvalid = (j0 + 63 <= TAU_ + i0 + 16 * w);   // wave-uniform
#pragma unroll
    for (int r = 0; r < 4; ++r) {
      int iL = 4 * g + r;
      int src = g * 16 + ((low + 15 - iL) & 15);   // D-layout: col=lane&15
      float sh0 = __shfl(p[0][r], src);
      float sh1 = __shfl(p[1][r], src);
      float sh2 = __shfl(p[2][r], src);
      float sh3 = __shfl(p[3][r], src);
      float sh4 = __shfl(p[4][r], src);
      bool lo = (low <= iL);
      float po0 = lo ? sh0 : sh1;
      float po1 = lo ? sh1 : sh2;
      float po2 = lo ? sh2 : sh3;
      float po3 = lo ? sh3 : sh4;
      if (fullvalid) {
        s4[0][r] = (s4[0][r] + po0) * SC_LOG2;
        s4[1][r] = (s4[1][r] + po1) * SC_LOG2;
        s4[2][r] = (s4[2][r] + po2) * SC_LOG2;
        s4[3][r] = (s4[3][r] + po3) * SC_LOG2;
      } else {
        int lim = TAU_ + i0 + 16 * w + iL;
        s4[0][r] = (j0 +  0 + low <= lim) ? (s4[0][r] + po0) * SC_LOG2 : -1e30f;
        s4[1][r] = (j0 + 16 + low <= lim) ? (s4[1][r] + po1) * SC_LOG2 : -1e30f;
        s4[2][r] = (j0 + 32 + low <= lim) ? (s4[2][r] + po2) * SC_LOG2 : -1e30f;
        s4[3][r] = (j0 + 48 + low <= lim) ? (s4[3][r] + po3) * SC_LOG2 : -1e30f;
      }
    }
    // ---- online softmax (exp2 domain, T13 defer-rescale THR=8) ----
#pragma unroll
    for (int r = 0; r < 4; ++r) {
      float mx = fmaxf(fmaxf(s4[0][r], s4[1][r]), fmaxf(s4[2][r], s4[3][r]));
      mx = fmaxf(mx, __shfl_xor(mx, 1));
      mx = fmaxf(mx, __shfl_xor(mx, 2));
      mx = fmaxf(mx, __shfl_xor(mx, 4));
      mx = fmaxf(mx, __shfl_xor(mx, 8));
      if (!__all(mx - mreg[r] <= 8.0f)) {    // rescale only on real max growth
        float mn = fmaxf(mreg[r], mx);
        float alpha = exp2f(mreg[r] - mn);
        mreg[r] = mn;
        lreg[r] *= alpha;
        O[0][r] *= alpha; O[1][r] *= alpha; O[2][r] *= alpha; O[3][r] *= alpha;
      }
      float sum = 0.f;
#pragma unroll
      for (int jt = 0; jt < 4; ++jt) {
        float pe = exp2f(s4[jt][r] - mreg[r]);   // bounded by 2^8 when deferred
        s4[jt][r] = pe;
        sum += pe;
      }
      sum += __shfl_xor(sum, 1);
      sum += __shfl_xor(sum, 2);
      sum += __shfl_xor(sum, 4);
      sum += __shfl_xor(sum, 8);
      lreg[r] += sum;
    }
    // ---- P -> bf16 LDS (C-layout -> A-layout transpose) ----
#pragma unroll
    for (int jt = 0; jt < 4; ++jt)
#pragma unroll
      for (int r = 0; r < 4; ++r)
        Pp[w][sw64(4 * g + r, jt * 16 + low)] = f2bf(s4[jt][r]);
    asm volatile("s_waitcnt lgkmcnt(0)" ::: "memory");
    s16x8 pa0 = *(const s16x8*)&Pp[w][sw64(low, 8 * g)];
    s16x8 pa1 = *(const s16x8*)&Pp[w][sw64(low, 32 + 8 * g)];
    // ---- PV ----
#pragma unroll
    for (int dt = 0; dt < 4; ++dt) {
      s16x8 v0 = *(const s16x8*)&Vt[cur][sw64(dt * 16 + low, 8 * g)];
      s16x8 v1 = *(const s16x8*)&Vt[cur][sw64(dt * 16 + low, 32 + 8 * g)];
      O[dt] = __builtin_amdgcn_mfma_f32_16x16x32_bf16(pa0, v0, O[dt], 0, 0, 0);
      O[dt] = __builtin_amdgcn_mfma_f32_16x16x32_bf16(pa1, v1, O[dt], 0, 0, 0);
    }
    if (more) vwrite(cur ^ 1);   // V transpose-write for next tile (late)
    __syncthreads();             // LDS reads done + DMA landed + V writes vis
    cur ^= 1;
  }
  // epilogue: normalize, store bf16 for the out-GEMM
  float inv[4];
#pragma unroll
  for (int r = 0; r < 4; ++r) inv[r] = 1.0f / lreg[r];
#pragma unroll
  for (int dt = 0; dt < 4; ++dt)
#pragma unroll
    for (int r = 0; r < 4; ++r)
      attn[((size_t)(b * T_ + i0 + 16 * w + 4 * g + r)) * 1024 +
           h * 64 + dt * 16 + low] = f2bf(O[dt][r] * inv[r]);
}

// ---------------------------------------------------------------------------
extern "C" void kernel_launch(void* const* d_in, const int* in_sizes, int n_in,
                              void* d_out, int out_size, void* d_ws, size_t ws_size,
                              hipStream_t stream) {
  const float* inputs = (const float*)d_in[0];
  const float* memory = (const float*)d_in[1];
  const float* w_qkv  = (const float*)d_in[2];
  const float* w_pos  = (const float*)d_in[3];
  const float* w_out  = (const float*)d_in[4];
  const float* uvar   = (const float*)d_in[5];
  const float* vvar   = (const float*)d_in[6];
  const float* gamma  = (const float*)d_in[7];
  const float* beta   = (const float*)d_in[8];
  float* out = (float*)d_out;

  // workspace layout, all bf16 (48.2 MB)
  ushort* qkvB = (ushort*)d_ws;                       // 4096*3072
  ushort* xnb  = qkvB + (size_t)4096 * 3072;          // 4096*1024
  ushort* phib = xnb  + (size_t)4096 * 1024;          // 1024*1024
  ushort* RmB  = phib + (size_t)1024 * 1024;          // 1024*1024
  ushort* wqb  = RmB  + (size_t)1024 * 1024;          // 3072*1024
  ushort* wpb  = wqb  + (size_t)3072 * 1024;          // 1024*1024
  ushort* wob  = wpb  + (size_t)1024 * 1024;          // 1024*1024
  ushort* attnb = xnb;                                // reuse after QKV GEMM

  prep_kernel<<<3328, 256, 0, stream>>>(inputs, memory, gamma, beta, xnb,
                                        phib, w_qkv, wqb, w_pos, wpb, w_out, wob);
  qkv_r_gemm<<<832, 256, 0, stream>>>(xnb, wqb, qkvB, phib, wpb, RmB);
  attn_mfma_kernel<<<dim3(B_ * H_ * 8), 256, 0, stream>>>(qkvB, RmB, uvar, vvar, attnb);
  out_gemm<<<256, 256, 0, stream>>>(attnb, wob, out);
}

// Round 12
// 193.908 us; speedup vs baseline: 1.0897x; 1.0897x over previous
//
#include <hip/hip_runtime.h>
#include <math.h>

#define B_   4
#define T_   512
#define TAU_ 512
#define L_   1024
#define DM_  1024
#define H_   16
#define D_   64

typedef short  s16x8 __attribute__((ext_vector_type(8)));   // 8 bf16 MFMA frag
typedef ushort u16x4 __attribute__((ext_vector_type(4)));
typedef float  f32x4 __attribute__((ext_vector_type(4)));

__device__ __forceinline__ ushort f2bf(float x) {   // RNE float->bf16 bits
  uint u = __float_as_uint(x);
  u += 0x7fffu + ((u >> 16) & 1u);
  return (ushort)(u >> 16);
}
__device__ __forceinline__ float bf2f(ushort u) {
  return __uint_as_float(((uint)u) << 16);
}
// XOR-swizzle for bf16 [rows][64] LDS tiles (128B rows): permute 16B slots by row&7
__device__ __forceinline__ int sw64(int row, int col) {
  return row * 64 + (col ^ ((row & 7) << 3));
}

// ---------------------------------------------------------------------------
// Fused preprocessing, launch-overhead-minimized (3328 blocks):
// [0,1024)    LayerNorm: one WAVE per row (4 rows/block, no barriers)
// [1024,2048) phi table: 4 elems/thread
// [2048,3328) weight fp32->bf16 casts: 4 float4/thread
// ---------------------------------------------------------------------------
__global__ __launch_bounds__(256) void prep_kernel(
    const float* __restrict__ inp, const float* __restrict__ mem,
    const float* __restrict__ gamma, const float* __restrict__ beta,
    ushort* __restrict__ xn, ushort* __restrict__ phi,
    const float* __restrict__ wq, ushort* __restrict__ wqb,
    const float* __restrict__ wp, ushort* __restrict__ wpb,
    const float* __restrict__ wo, ushort* __restrict__ wob) {
  int blk = blockIdx.x;
  int t = threadIdx.x;
  if (blk < 1024) {                    // ---- LayerNorm, wave per row ----
    int wid = t >> 6, lane = t & 63;
    int row = blk * 4 + wid;           // b*L + l
    int b = row >> 10, l = row & 1023;
    const float* src = (l < TAU_)
        ? mem + ((size_t)b * TAU_ + l) * DM_
        : inp + ((size_t)b * T_ + (l - TAU_)) * DM_;
    float4 v[4];
    float s1 = 0.f, s2 = 0.f;
#pragma unroll
    for (int c = 0; c < 4; ++c) {
      v[c] = *(const float4*)(src + c * 256 + lane * 4);
      s1 += v[c].x + v[c].y + v[c].z + v[c].w;
      s2 += v[c].x * v[c].x + v[c].y * v[c].y + v[c].z * v[c].z + v[c].w * v[c].w;
    }
#pragma unroll
    for (int off = 32; off > 0; off >>= 1) {
      s1 += __shfl_xor(s1, off);
      s2 += __shfl_xor(s2, off);
    }
    float mu   = s1 * (1.0f / DM_);
    float var  = s2 * (1.0f / DM_) - mu * mu;
    float rstd = 1.0f / sqrtf(var + 1e-5f);
#pragma unroll
    for (int c = 0; c < 4; ++c) {
      float4 g  = *(const float4*)(gamma + c * 256 + lane * 4);
      float4 be = *(const float4*)(beta  + c * 256 + lane * 4);
      u16x4 o;
      o[0] = f2bf((v[c].x - mu) * rstd * g.x + be.x);
      o[1] = f2bf((v[c].y - mu) * rstd * g.y + be.y);
      o[2] = f2bf((v[c].z - mu) * rstd * g.z + be.z);
      o[3] = f2bf((v[c].w - mu) * rstd * g.w + be.w);
      *(u16x4*)(xn + (size_t)row * DM_ + c * 256 + lane * 4) = o;
    }
  } else if (blk < 2048) {             // ---- phi ----
    int base = (blk - 1024) * 1024 + t;
#pragma unroll
    for (int it = 0; it < 4; ++it) {
      int idx = base + it * 256;       // 0 .. 1M-1
      int m = idx >> 10, c = idx & 1023;
      float p = (float)(1023 - m);
      int cc = (c < 512) ? c : c - 512;
      float invf = __expf(-((float)(2 * cc) * (1.0f / 1024.0f)) * 9.210340371976184f);
      float a = p * invf;
      phi[idx] = f2bf((c < 512) ? __sinf(a) : __cosf(a));
    }
  } else {                             // ---- weight casts ----
    int base = (blk - 2048) * 1024 + t;   // float4-group index
#pragma unroll
    for (int it = 0; it < 4; ++it) {
      int i = base + it * 256;            // < 1310720 exactly
      const float* src; ushort* dst; int off;
      if (i < 786432)       { src = wq; dst = wqb; off = i; }
      else if (i < 1048576) { src = wp; dst = wpb; off = i - 786432; }
      else                  { src = wo; dst = wob; off = i - 1048576; }
      float4 v = *(const float4*)(src + (size_t)off * 4);
      u16x4 o = { f2bf(v.x), f2bf(v.y), f2bf(v.z), f2bf(v.w) };
      *(u16x4*)(dst + (size_t)off * 4) = o;
    }
  }
}

// ---------------------------------------------------------------------------
// bf16 MFMA NT GEMM, 128x64 tile, BK=64, 24KB LDS -> 6 blocks/CU.
// Wave 2x2 grid, each 64 rows x 32 cols (acc[4][2]). Both-sides slot swizzle.
// Used for ALL GEMMs: latency hiding via block TLP (measured positive on
// out_gemm round 8; qkv_r was grid-limited at 3.25 blocks/CU with BN=128).
// ---------------------------------------------------------------------------
template <typename CT>
__device__ __forceinline__ void gemm_nt_body_n64(
    const ushort* __restrict__ A, const ushort* __restrict__ B,
    CT* __restrict__ C, int M, int N, int K, int bx, int by) {
  __shared__ __attribute__((aligned(16))) ushort As[128 * 64];
  __shared__ __attribute__((aligned(16))) ushort Bs[64 * 64];
  int t = threadIdx.x;
  int w = t >> 6, lane = t & 63, g = lane >> 4, low = lane & 15;
  int wr = w >> 1, wc = w & 1;               // each wave: 64 rows x 32 cols
  int m0 = by * 128, n0 = bx * 64;
  f32x4 acc[4][2] = {};

  for (int kt = 0; kt < K; kt += 64) {
    __syncthreads();
#pragma unroll
    for (int q = 0; q < 4; ++q) {            // A: 1024 chunks
      int c = t + q * 256;
      int row = c >> 3;
      int gslot = (c & 7) ^ (row & 7);
      const ushort* ga = A + (size_t)(m0 + row) * K + kt + gslot * 8;
      __builtin_amdgcn_global_load_lds(
          (const __attribute__((address_space(1))) void*)ga,
          (__attribute__((address_space(3))) void*)&As[(q * 256 + w * 64) * 8],
          16, 0, 0);
    }
#pragma unroll
    for (int q = 0; q < 2; ++q) {            // B: 512 chunks
      int c = t + q * 256;
      int row = c >> 3;
      int gslot = (c & 7) ^ (row & 7);
      const ushort* gb = B + (size_t)(n0 + row) * K + kt + gslot * 8;
      __builtin_amdgcn_global_load_lds(
          (const __attribute__((address_space(1))) void*)gb,
          (__attribute__((address_space(3))) void*)&Bs[(q * 256 + w * 64) * 8],
          16, 0, 0);
    }
    __syncthreads();

#pragma unroll
    for (int kc = 0; kc < 2; ++kc) {
      s16x8 af[4], bfr[2];
#pragma unroll
      for (int mi = 0; mi < 4; ++mi) {
        int row = wr * 64 + mi * 16 + low;
        af[mi] = *(const s16x8*)&As[row * 64 + (((4 * kc + g) ^ (row & 7)) * 8)];
      }
#pragma unroll
      for (int ni = 0; ni < 2; ++ni) {
        int col = wc * 32 + ni * 16 + low;
        bfr[ni] = *(const s16x8*)&Bs[col * 64 + (((4 * kc + g) ^ (col & 7)) * 8)];
      }
#pragma unroll
      for (int mi = 0; mi < 4; ++mi)
#pragma unroll
        for (int ni = 0; ni < 2; ++ni)
          acc[mi][ni] = __builtin_amdgcn_mfma_f32_16x16x32_bf16(
              af[mi], bfr[ni], acc[mi][ni], 0, 0, 0);
    }
  }
#pragma unroll
  for (int mi = 0; mi < 4; ++mi)
#pragma unroll
    for (int ni = 0; ni < 2; ++ni)
#pragma unroll
      for (int r = 0; r < 4; ++r) {
        int m = m0 + wr * 64 + mi * 16 + 4 * g + r;
        int n = n0 + wc * 32 + ni * 16 + low;
        if constexpr (sizeof(CT) == 2)
          C[(size_t)m * N + n] = f2bf(acc[mi][ni][r]);
        else
          C[(size_t)m * N + n] = acc[mi][ni][r];
      }
}

// QKV GEMM (1536 tiles of 128x64) + R GEMM (128 tiles) in one 1664-block
// dispatch = 6.5 blocks/CU (was 832 = 3.25). Bijective XCD swizzle (8 x 208).
__global__ __launch_bounds__(256) void qkv_r_gemm(
    const ushort* __restrict__ xnb, const ushort* __restrict__ wqb,
    ushort* __restrict__ qkvB,
    const ushort* __restrict__ phib, const ushort* __restrict__ wpb,
    ushort* __restrict__ RmB) {
  int orig = blockIdx.x;
  int id = (orig & 7) * 208 + (orig >> 3);
  if (id < 1536)
    gemm_nt_body_n64<ushort>(xnb, wqb, qkvB, 4096, 3072, 1024, id % 48, id / 48);
  else {
    id -= 1536;
    gemm_nt_body_n64<ushort>(phib, wpb, RmB, 1024, 1024, 1024, id % 16, id / 16);
  }
}

// out GEMM with 128x64 tiles: 256 blocks = 1/CU.
__global__ __launch_bounds__(256) void out_gemm(
    const ushort* __restrict__ attnb, const ushort* __restrict__ wob,
    float* __restrict__ out) {
  int orig = blockIdx.x;                     // 256 = 8 x 32
  int id = (orig & 7) * 32 + (orig >> 3);
  gemm_nt_body_n64<float>(attnb, wob, out, 2048, 1024, 1024, id % 16, id / 16);
}

// ---------------------------------------------------------------------------
// MFMA bf16 flash attention with rel-shift — round-10 exact (best measured,
// 100 VGPR): XCD family swizzle + in-kernel V transpose + K/R DMA dbuf,
// plain __expf softmax. Round-11 trims (exp2/defer/mask-skip) REGRESSED
// (+16 VGPR, +4us) — do not reapply.
// ---------------------------------------------------------------------------
__global__ __launch_bounds__(256) void attn_mfma_kernel(
    const ushort* __restrict__ qkv, const ushort* __restrict__ Rm,
    const float* __restrict__ uvar, const float* __restrict__ vvar,
    ushort* __restrict__ attn) {
  __shared__ __attribute__((aligned(16))) ushort Ks[2][64 * 64];
  __shared__ __attribute__((aligned(16))) ushort Vt[2][64 * 64];
  __shared__ __attribute__((aligned(16))) ushort Rs[2][128 * 64];
  __shared__ __attribute__((aligned(16))) ushort Pp[4][16 * 64];

  int t   = threadIdx.x;
  int w   = t >> 6;          // wave 0..3
  int lw  = t & 63;
  int g   = lw >> 4;         // k-group 0..3
  int low = lw & 15;

  int orig = blockIdx.x;     // XCD of a block = orig & 7 (round-robin model)
  int bid  = (orig & 7) * 64 + (orig >> 3);   // XCD owns 64 consecutive bids
  int s    = bid & 7;                         // bi-slot within (b,h) family
  int h    = (bid >> 3) & 15;
  int b    = bid >> 7;
  int bi   = (s & 1) ? (7 - (s >> 1)) : (s >> 1);  // pairs (0,7)(1,6)(2,5)(3,4)
  int i0   = bi * 64;
  int lb_w = 48 - 16 * w;    // wave's P m-window base within Rs

  auto stage_kr = [&](int buf, int tl) {
    int j0s = tl * 64;
#pragma unroll
    for (int q = 0; q < 2; ++q) {
      int c = t + q * 256;                  // 16B chunk id 0..511
      int row = c >> 3;
      int sl = (c & 7) ^ (row & 7);
      const ushort* srck = qkv + (size_t)(b * L_ + j0s + row) * 3072 +
                           1024 + h * 64 + sl * 8;
      __builtin_amdgcn_global_load_lds(
          (const __attribute__((address_space(1))) void*)srck,
          (__attribute__((address_space(3))) void*)&Ks[buf][(q * 256 + w * 64) * 8],
          16, 0, 0);
    }
    int mb = j0s + 448 - i0;
#pragma unroll
    for (int q = 0; q < 4; ++q) {
      int c = t + q * 256;                  // chunk 0..1023
      int row = c >> 3;                     // R row 0..127
      int m = mb + row; m = (m > 1023) ? 1023 : m;
      int sl = (c & 7) ^ (row & 7);
      const ushort* srcr = Rm + (size_t)m * 1024 + h * 64 + sl * 8;
      __builtin_amdgcn_global_load_lds(
          (const __attribute__((address_space(1))) void*)srcr,
          (__attribute__((address_space(3))) void*)&Rs[buf][(q * 256 + w * 64) * 8],
          16, 0, 0);
    }
  };

  // V staging: reg-load (issue early) ...
  int vj  = t & 63;                         // wave-local j column
  int vd0 = (t >> 6) * 8;                   // wave-uniform d base (0,8,16,24)
  float4 vreg[2];
  auto vload = [&](int tl) {
    const ushort* p = qkv + (size_t)(b * L_ + tl * 64 + vj) * 3072 + 2048 + h * 64;
    vreg[0] = *(const float4*)(p + vd0);
    vreg[1] = *(const float4*)(p + vd0 + 32);
  };
  // ... transpose-write late (d rows wave-uniform: 64 lanes x 2B = no conflict)
  auto vwrite = [&](int buf) {
#pragma unroll
    for (int it = 0; it < 2; ++it) {
      ushort vals[8];
      *(float4*)vals = vreg[it];
#pragma unroll
      for (int e = 0; e < 8; ++e) {
        int d = it * 32 + vd0 + e;
        Vt[buf][d * 64 + (vj ^ ((d & 7) << 3))] = vals[e];
      }
    }
  };

  // Q fragments (bf16 source + fp32 u/v), loaded once
  int iq = i0 + 16 * w + low;
  s16x8 qu[2], qv[2];
  {
    const ushort* qrow = qkv + (size_t)(b * L_ + TAU_ + iq) * 3072 + h * 64;
    const float* ur = uvar + h * 64;
    const float* vr = vvar + h * 64;
#pragma unroll
    for (int kc = 0; kc < 2; ++kc) {
      int dbase = kc * 32 + 8 * g;
#pragma unroll
      for (int e = 0; e < 8; ++e) {
        float q = bf2f(qrow[dbase + e]);
        qu[kc][e] = (short)f2bf(q + ur[dbase + e]);
        qv[kc][e] = (short)f2bf(q + vr[dbase + e]);
      }
    }
  }

  f32x4 O[4] = {};
  float mreg[4] = {-INFINITY, -INFINITY, -INFINITY, -INFINITY};
  float lreg[4] = {0.f, 0.f, 0.f, 0.f};

  int ntiles = 9 + bi;       // covers j <= TAU + i0 + 63 exactly
  stage_kr(0, 0);
  vload(0);
  vwrite(0);                 // compiler inserts vmcnt wait on vreg use
  __syncthreads();           // drains DMA + LDS writes: tile 0 ready
  int cur = 0;
  for (int tile = 0; tile < ntiles; ++tile) {
    int j0 = tile * 64;
    bool more = (tile + 1 < ntiles);
    if (more) { stage_kr(cur ^ 1, tile + 1); vload(tile + 1); }

    // ---- QK^T ----
    f32x4 s4[4] = {};
#pragma unroll
    for (int jt = 0; jt < 4; ++jt) {
#pragma unroll
      for (int kc = 0; kc < 2; ++kc) {
        s16x8 kb = *(const s16x8*)&Ks[cur][sw64(jt * 16 + low, kc * 32 + 8 * g)];
        s4[jt] = __builtin_amdgcn_mfma_f32_16x16x32_bf16(qu[kc], kb, s4[jt], 0, 0, 0);
      }
    }
    // ---- P = (q+v)·R over the wave's 80-col m-window ----
    f32x4 p[5] = {};
#pragma unroll
    for (int mt = 0; mt < 5; ++mt) {
#pragma unroll
      for (int kc = 0; kc < 2; ++kc) {
        s16x8 rb = *(const s16x8*)&Rs[cur][sw64(lb_w + mt * 16 + low, kc * 32 + 8 * g)];
        p[mt] = __builtin_amdgcn_mfma_f32_16x16x32_bf16(qv[kc], rb, p[mt], 0, 0, 0);
      }
    }
    // ---- rel-shift via shfl + mask ----
#pragma unroll
    for (int r = 0; r < 4; ++r) {
      int iL = 4 * g + r;
      int src = g * 16 + ((low + 15 - iL) & 15);   // D-layout: col=lane&15
      float sh0 = __shfl(p[0][r], src);
      float sh1 = __shfl(p[1][r], src);
      float sh2 = __shfl(p[2][r], src);
      float sh3 = __shfl(p[3][r], src);
      float sh4 = __shfl(p[4][r], src);
      bool lo = (low <= iL);
      float po0 = lo ? sh0 : sh1;
      float po1 = lo ? sh1 : sh2;
      float po2 = lo ? sh2 : sh3;
      float po3 = lo ? sh3 : sh4;
      int lim = TAU_ + i0 + 16 * w + iL;
      s4[0][r] = (j0 +  0 + low <= lim) ? (s4[0][r] + po0) * 0.125f : -1e30f;
      s4[1][r] = (j0 + 16 + low <= lim) ? (s4[1][r] + po1) * 0.125f : -1e30f;
      s4[2][r] = (j0 + 32 + low <= lim) ? (s4[2][r] + po2) * 0.125f : -1e30f;
      s4[3][r] = (j0 + 48 + low <= lim) ? (s4[3][r] + po3) * 0.125f : -1e30f;
    }
    // ---- online softmax ----
#pragma unroll
    for (int r = 0; r < 4; ++r) {
      float mx = fmaxf(fmaxf(s4[0][r], s4[1][r]), fmaxf(s4[2][r], s4[3][r]));
      mx = fmaxf(mx, __shfl_xor(mx, 1));
      mx = fmaxf(mx, __shfl_xor(mx, 2));
      mx = fmaxf(mx, __shfl_xor(mx, 4));
      mx = fmaxf(mx, __shfl_xor(mx, 8));
      float mn = fmaxf(mreg[r], mx);
      float alpha = __expf(mreg[r] - mn);
      mreg[r] = mn;
      float sum = 0.f;
#pragma unroll
      for (int jt = 0; jt < 4; ++jt) {
        float pe = __expf(s4[jt][r] - mn);
        s4[jt][r] = pe;
        sum += pe;
      }
      sum += __shfl_xor(sum, 1);
      sum += __shfl_xor(sum, 2);
      sum += __shfl_xor(sum, 4);
      sum += __shfl_xor(sum, 8);
      lreg[r] = lreg[r] * alpha + sum;
      O[0][r] *= alpha; O[1][r] *= alpha; O[2][r] *= alpha; O[3][r] *= alpha;
    }
    // ---- P -> bf16 LDS (C-layout -> A-layout transpose) ----
#pragma unroll
    for (int jt = 0; jt < 4; ++jt)
#pragma unroll
      for (int r = 0; r < 4; ++r)
        Pp[w][sw64(4 * g + r, jt * 16 + low)] = f2bf(s4[jt][r]);
    asm volatile("s_waitcnt lgkmcnt(0)" ::: "memory");
    s16x8 pa0 = *(const s16x8*)&Pp[w][sw64(low, 8 * g)];
    s16x8 pa1 = *(const s16x8*)&Pp[w][sw64(low, 32 + 8 * g)];
    // ---- PV ----
#pragma unroll
    for (int dt = 0; dt < 4; ++dt) {
      s16x8 v0 = *(const s16x8*)&Vt[cur][sw64(dt * 16 + low, 8 * g)];
      s16x8 v1 = *(const s16x8*)&Vt[cur][sw64(dt * 16 + low, 32 + 8 * g)];
      O[dt] = __builtin_amdgcn_mfma_f32_16x16x32_bf16(pa0, v0, O[dt], 0, 0, 0);
      O[dt] = __builtin_amdgcn_mfma_f32_16x16x32_bf16(pa1, v1, O[dt], 0, 0, 0);
    }
    if (more) vwrite(cur ^ 1);   // V transpose-write for next tile (late)
    __syncthreads();             // LDS reads done + DMA landed + V writes vis
    cur ^= 1;
  }
  // epilogue: normalize, store bf16 for the out-GEMM
  float inv[4];
#pragma unroll
  for (int r = 0; r < 4; ++r) inv[r] = 1.0f / lreg[r];
#pragma unroll
  for (int dt = 0; dt < 4; ++dt)
#pragma unroll
    for (int r = 0; r < 4; ++r)
      attn[((size_t)(b * T_ + i0 + 16 * w + 4 * g + r)) * 1024 +
           h * 64 + dt * 16 + low] = f2bf(O[dt][r] * inv[r]);
}

// ---------------------------------------------------------------------------
extern "C" void kernel_launch(void* const* d_in, const int* in_sizes, int n_in,
                              void* d_out, int out_size, void* d_ws, size_t ws_size,
                              hipStream_t stream) {
  const float* inputs = (const float*)d_in[0];
  const float* memory = (const float*)d_in[1];
  const float* w_qkv  = (const float*)d_in[2];
  const float* w_pos  = (const float*)d_in[3];
  const float* w_out  = (const float*)d_in[4];
  const float* uvar   = (const float*)d_in[5];
  const float* vvar   = (const float*)d_in[6];
  const float* gamma  = (const float*)d_in[7];
  const float* beta   = (const float*)d_in[8];
  float* out = (float*)d_out;

  // workspace layout, all bf16 (48.2 MB)
  ushort* qkvB = (ushort*)d_ws;                       // 4096*3072
  ushort* xnb  = qkvB + (size_t)4096 * 3072;          // 4096*1024
  ushort* phib = xnb  + (size_t)4096 * 1024;          // 1024*1024
  ushort* RmB  = phib + (size_t)1024 * 1024;          // 1024*1024
  ushort* wqb  = RmB  + (size_t)1024 * 1024;          // 3072*1024
  ushort* wpb  = wqb  + (size_t)3072 * 1024;          // 1024*1024
  ushort* wob  = wpb  + (size_t)1024 * 1024;          // 1024*1024
  ushort* attnb = xnb;                                // reuse after QKV GEMM

  prep_kernel<<<3328, 256, 0, stream>>>(inputs, memory, gamma, beta, xnb,
                                        phib, w_qkv, wqb, w_pos, wpb, w_out, wob);
  qkv_r_gemm<<<1664, 256, 0, stream>>>(xnb, wqb, qkvB, phib, wpb, RmB);
  attn_mfma_kernel<<<dim3(B_ * H_ * 8), 256, 0, stream>>>(qkvB, RmB, uvar, vvar, attnb);
  out_gemm<<<256, 256, 0, stream>>>(attnb, wob, out);
}

// Round 13
// 190.769 us; speedup vs baseline: 1.1076x; 1.0165x over previous
//
#include <hip/hip_runtime.h>
#include <math.h>

#define B_   4
#define T_   512
#define TAU_ 512
#define L_   1024
#define DM_  1024
#define H_   16
#define D_   64

typedef short  s16x8 __attribute__((ext_vector_type(8)));   // 8 bf16 MFMA frag
typedef ushort u16x4 __attribute__((ext_vector_type(4)));
typedef float  f32x4 __attribute__((ext_vector_type(4)));

__device__ __forceinline__ ushort f2bf(float x) {   // RNE float->bf16 bits
  uint u = __float_as_uint(x);
  u += 0x7fffu + ((u >> 16) & 1u);
  return (ushort)(u >> 16);
}
__device__ __forceinline__ float bf2f(ushort u) {
  return __uint_as_float(((uint)u) << 16);
}
// XOR-swizzle for bf16 [rows][64] LDS tiles (128B rows): permute 16B slots by row&7
__device__ __forceinline__ int sw64(int row, int col) {
  return row * 64 + (col ^ ((row & 7) << 3));
}

// ---------------------------------------------------------------------------
// Fused preprocessing, launch-overhead-minimized (3328 blocks):
// [0,1024)    LayerNorm: one WAVE per row (4 rows/block, no barriers)
// [1024,2048) phi table: 4 elems/thread
// [2048,3328) weight fp32->bf16 casts: 4 float4/thread
// ---------------------------------------------------------------------------
__global__ __launch_bounds__(256) void prep_kernel(
    const float* __restrict__ inp, const float* __restrict__ mem,
    const float* __restrict__ gamma, const float* __restrict__ beta,
    ushort* __restrict__ xn, ushort* __restrict__ phi,
    const float* __restrict__ wq, ushort* __restrict__ wqb,
    const float* __restrict__ wp, ushort* __restrict__ wpb,
    const float* __restrict__ wo, ushort* __restrict__ wob) {
  int blk = blockIdx.x;
  int t = threadIdx.x;
  if (blk < 1024) {                    // ---- LayerNorm, wave per row ----
    int wid = t >> 6, lane = t & 63;
    int row = blk * 4 + wid;           // b*L + l
    int b = row >> 10, l = row & 1023;
    const float* src = (l < TAU_)
        ? mem + ((size_t)b * TAU_ + l) * DM_
        : inp + ((size_t)b * T_ + (l - TAU_)) * DM_;
    float4 v[4];
    float s1 = 0.f, s2 = 0.f;
#pragma unroll
    for (int c = 0; c < 4; ++c) {
      v[c] = *(const float4*)(src + c * 256 + lane * 4);
      s1 += v[c].x + v[c].y + v[c].z + v[c].w;
      s2 += v[c].x * v[c].x + v[c].y * v[c].y + v[c].z * v[c].z + v[c].w * v[c].w;
    }
#pragma unroll
    for (int off = 32; off > 0; off >>= 1) {
      s1 += __shfl_xor(s1, off);
      s2 += __shfl_xor(s2, off);
    }
    float mu   = s1 * (1.0f / DM_);
    float var  = s2 * (1.0f / DM_) - mu * mu;
    float rstd = 1.0f / sqrtf(var + 1e-5f);
#pragma unroll
    for (int c = 0; c < 4; ++c) {
      float4 g  = *(const float4*)(gamma + c * 256 + lane * 4);
      float4 be = *(const float4*)(beta  + c * 256 + lane * 4);
      u16x4 o;
      o[0] = f2bf((v[c].x - mu) * rstd * g.x + be.x);
      o[1] = f2bf((v[c].y - mu) * rstd * g.y + be.y);
      o[2] = f2bf((v[c].z - mu) * rstd * g.z + be.z);
      o[3] = f2bf((v[c].w - mu) * rstd * g.w + be.w);
      *(u16x4*)(xn + (size_t)row * DM_ + c * 256 + lane * 4) = o;
    }
  } else if (blk < 2048) {             // ---- phi ----
    int base = (blk - 1024) * 1024 + t;
#pragma unroll
    for (int it = 0; it < 4; ++it) {
      int idx = base + it * 256;       // 0 .. 1M-1
      int m = idx >> 10, c = idx & 1023;
      float p = (float)(1023 - m);
      int cc = (c < 512) ? c : c - 512;
      float invf = __expf(-((float)(2 * cc) * (1.0f / 1024.0f)) * 9.210340371976184f);
      float a = p * invf;
      phi[idx] = f2bf((c < 512) ? __sinf(a) : __cosf(a));
    }
  } else {                             // ---- weight casts ----
    int base = (blk - 2048) * 1024 + t;   // float4-group index
#pragma unroll
    for (int it = 0; it < 4; ++it) {
      int i = base + it * 256;            // < 1310720 exactly
      const float* src; ushort* dst; int off;
      if (i < 786432)       { src = wq; dst = wqb; off = i; }
      else if (i < 1048576) { src = wp; dst = wpb; off = i - 786432; }
      else                  { src = wo; dst = wob; off = i - 1048576; }
      float4 v = *(const float4*)(src + (size_t)off * 4);
      u16x4 o = { f2bf(v.x), f2bf(v.y), f2bf(v.z), f2bf(v.w) };
      *(u16x4*)(dst + (size_t)off * 4) = o;
    }
  }
}

// ---------------------------------------------------------------------------
// bf16 MFMA NT GEMM, 128x64 tile, BK=64, 24KB LDS -> 6 blocks/CU.
// Generalized to pre-offset bases: Arows -> tile row 0 of A (lda = K),
// Brows -> tile col 0's B row (ldb = K), Crows -> tile (row0, col0), ldc.
// Wave 2x2 grid, each 64 rows x 32 cols (acc[4][2]). Both-sides slot swizzle.
// ---------------------------------------------------------------------------
template <typename CT>
__device__ __forceinline__ void gemm_nt_body_n64(
    const ushort* __restrict__ Arows, const ushort* __restrict__ Brows,
    CT* __restrict__ Crows, int ldc, int K) {
  __shared__ __attribute__((aligned(16))) ushort As[128 * 64];
  __shared__ __attribute__((aligned(16))) ushort Bs[64 * 64];
  int t = threadIdx.x;
  int w = t >> 6, lane = t & 63, g = lane >> 4, low = lane & 15;
  int wr = w >> 1, wc = w & 1;               // each wave: 64 rows x 32 cols
  f32x4 acc[4][2] = {};

  for (int kt = 0; kt < K; kt += 64) {
    __syncthreads();
#pragma unroll
    for (int q = 0; q < 4; ++q) {            // A: 1024 chunks
      int c = t + q * 256;
      int row = c >> 3;
      int gslot = (c & 7) ^ (row & 7);
      const ushort* ga = Arows + (size_t)row * K + kt + gslot * 8;
      __builtin_amdgcn_global_load_lds(
          (const __attribute__((address_space(1))) void*)ga,
          (__attribute__((address_space(3))) void*)&As[(q * 256 + w * 64) * 8],
          16, 0, 0);
    }
#pragma unroll
    for (int q = 0; q < 2; ++q) {            // B: 512 chunks
      int c = t + q * 256;
      int row = c >> 3;
      int gslot = (c & 7) ^ (row & 7);
      const ushort* gb = Brows + (size_t)row * K + kt + gslot * 8;
      __builtin_amdgcn_global_load_lds(
          (const __attribute__((address_space(1))) void*)gb,
          (__attribute__((address_space(3))) void*)&Bs[(q * 256 + w * 64) * 8],
          16, 0, 0);
    }
    __syncthreads();

#pragma unroll
    for (int kc = 0; kc < 2; ++kc) {
      s16x8 af[4], bfr[2];
#pragma unroll
      for (int mi = 0; mi < 4; ++mi) {
        int row = wr * 64 + mi * 16 + low;
        af[mi] = *(const s16x8*)&As[row * 64 + (((4 * kc + g) ^ (row & 7)) * 8)];
      }
#pragma unroll
      for (int ni = 0; ni < 2; ++ni) {
        int col = wc * 32 + ni * 16 + low;
        bfr[ni] = *(const s16x8*)&Bs[col * 64 + (((4 * kc + g) ^ (col & 7)) * 8)];
      }
#pragma unroll
      for (int mi = 0; mi < 4; ++mi)
#pragma unroll
        for (int ni = 0; ni < 2; ++ni)
          acc[mi][ni] = __builtin_amdgcn_mfma_f32_16x16x32_bf16(
              af[mi], bfr[ni], acc[mi][ni], 0, 0, 0);
    }
  }
#pragma unroll
  for (int mi = 0; mi < 4; ++mi)
#pragma unroll
    for (int ni = 0; ni < 2; ++ni)
#pragma unroll
      for (int r = 0; r < 4; ++r) {
        int m = wr * 64 + mi * 16 + 4 * g + r;          // 0..127 tile-local
        int n = wc * 32 + ni * 16 + low;                // 0..63 tile-local
        if constexpr (sizeof(CT) == 2)
          Crows[(size_t)m * ldc + n] = f2bf(acc[mi][ni][r]);
        else
          Crows[(size_t)m * ldc + n] = acc[mi][ni][r];
      }
}

// ---------------------------------------------------------------------------
// Fused projection GEMMs, dead-Q-work eliminated (-17% FLOP vs full QKV):
//   [0,1024)    KV-GEMM : xn[4096] x w_kv[2048]  -> qkvB cols 1024..3071
//   [1024,1280) Q-GEMM  : xn(input rows only, 2048) x w_q[1024] -> cols 0..1023
//   [1280,1408) R-GEMM  : phi[1024] x w_pos[1024] -> RmB
// 1408 blocks = 8 x 176 bijective XCD swizzle. Each Q tile sits inside one
// batch's 512-row input span (512 % 128 == 0) -> row remap is a base offset.
// ---------------------------------------------------------------------------
__global__ __launch_bounds__(256) void qkv_r_gemm(
    const ushort* __restrict__ xnb, const ushort* __restrict__ wqb,
    ushort* __restrict__ qkvB,
    const ushort* __restrict__ phib, const ushort* __restrict__ wpb,
    ushort* __restrict__ RmB) {
  int orig = blockIdx.x;
  int id = (orig & 7) * 176 + (orig >> 3);
  if (id < 1024) {                     // KV: 32 row-tiles x 32 col-tiles
    int by = id >> 5, bx = id & 31;
    gemm_nt_body_n64<ushort>(
        xnb + (size_t)by * 128 * 1024,
        wqb + (size_t)(1024 + bx * 64) * 1024,
        qkvB + (size_t)by * 128 * 3072 + 1024 + bx * 64, 3072, 1024);
  } else if (id < 1280) {              // Q: 16 row-tiles (2048 rows) x 16 col
    int q = id - 1024;
    int by = q >> 4, bx = q & 15;
    int b = by >> 2;                   // batch; 4 tiles per 512-row span
    size_t arow = (size_t)b * 1024 + 512 + (by & 3) * 128;
    gemm_nt_body_n64<ushort>(
        xnb + arow * 1024,
        wqb + (size_t)bx * 64 * 1024,
        qkvB + arow * 3072 + bx * 64, 3072, 1024);
  } else {                             // R: 8 row-tiles x 16 col-tiles
    int rr = id - 1280;
    int by = rr >> 4, bx = rr & 15;
    gemm_nt_body_n64<ushort>(
        phib + (size_t)by * 128 * 1024,
        wpb + (size_t)bx * 64 * 1024,
        RmB + (size_t)by * 128 * 1024 + bx * 64, 1024, 1024);
  }
}

// out GEMM: 2048x1024, 128x64 tiles -> 256 blocks (8 x 32 XCD swizzle).
__global__ __launch_bounds__(256) void out_gemm(
    const ushort* __restrict__ attnb, const ushort* __restrict__ wob,
    float* __restrict__ out) {
  int orig = blockIdx.x;
  int id = (orig & 7) * 32 + (orig >> 3);
  int by = id >> 4, bx = id & 15;
  gemm_nt_body_n64<float>(
      attnb + (size_t)by * 128 * 1024,
      wob + (size_t)bx * 64 * 1024,
      out + (size_t)by * 128 * 1024 + bx * 64, 1024, 1024);
}

// ---------------------------------------------------------------------------
// MFMA bf16 flash attention with rel-shift — round-10 exact (best measured,
// 100 VGPR, local optimum — 8 perturbations tested, all neutral/negative):
// XCD family swizzle + in-kernel V transpose + K/R DMA dbuf, __expf softmax.
// ---------------------------------------------------------------------------
__global__ __launch_bounds__(256) void attn_mfma_kernel(
    const ushort* __restrict__ qkv, const ushort* __restrict__ Rm,
    const float* __restrict__ uvar, const float* __restrict__ vvar,
    ushort* __restrict__ attn) {
  __shared__ __attribute__((aligned(16))) ushort Ks[2][64 * 64];
  __shared__ __attribute__((aligned(16))) ushort Vt[2][64 * 64];
  __shared__ __attribute__((aligned(16))) ushort Rs[2][128 * 64];
  __shared__ __attribute__((aligned(16))) ushort Pp[4][16 * 64];

  int t   = threadIdx.x;
  int w   = t >> 6;          // wave 0..3
  int lw  = t & 63;
  int g   = lw >> 4;         // k-group 0..3
  int low = lw & 15;

  int orig = blockIdx.x;     // XCD of a block = orig & 7 (round-robin model)
  int bid  = (orig & 7) * 64 + (orig >> 3);   // XCD owns 64 consecutive bids
  int s    = bid & 7;                         // bi-slot within (b,h) family
  int h    = (bid >> 3) & 15;
  int b    = bid >> 7;
  int bi   = (s & 1) ? (7 - (s >> 1)) : (s >> 1);  // pairs (0,7)(1,6)(2,5)(3,4)
  int i0   = bi * 64;
  int lb_w = 48 - 16 * w;    // wave's P m-window base within Rs

  auto stage_kr = [&](int buf, int tl) {
    int j0s = tl * 64;
#pragma unroll
    for (int q = 0; q < 2; ++q) {
      int c = t + q * 256;                  // 16B chunk id 0..511
      int row = c >> 3;
      int sl = (c & 7) ^ (row & 7);
      const ushort* srck = qkv + (size_t)(b * L_ + j0s + row) * 3072 +
                           1024 + h * 64 + sl * 8;
      __builtin_amdgcn_global_load_lds(
          (const __attribute__((address_space(1))) void*)srck,
          (__attribute__((address_space(3))) void*)&Ks[buf][(q * 256 + w * 64) * 8],
          16, 0, 0);
    }
    int mb = j0s + 448 - i0;
#pragma unroll
    for (int q = 0; q < 4; ++q) {
      int c = t + q * 256;                  // chunk 0..1023
      int row = c >> 3;                     // R row 0..127
      int m = mb + row; m = (m > 1023) ? 1023 : m;
      int sl = (c & 7) ^ (row & 7);
      const ushort* srcr = Rm + (size_t)m * 1024 + h * 64 + sl * 8;
      __builtin_amdgcn_global_load_lds(
          (const __attribute__((address_space(1))) void*)srcr,
          (__attribute__((address_space(3))) void*)&Rs[buf][(q * 256 + w * 64) * 8],
          16, 0, 0);
    }
  };

  // V staging: reg-load (issue early) ...
  int vj  = t & 63;                         // wave-local j column
  int vd0 = (t >> 6) * 8;                   // wave-uniform d base (0,8,16,24)
  float4 vreg[2];
  auto vload = [&](int tl) {
    const ushort* p = qkv + (size_t)(b * L_ + tl * 64 + vj) * 3072 + 2048 + h * 64;
    vreg[0] = *(const float4*)(p + vd0);
    vreg[1] = *(const float4*)(p + vd0 + 32);
  };
  // ... transpose-write late (d rows wave-uniform: 64 lanes x 2B = no conflict)
  auto vwrite = [&](int buf) {
#pragma unroll
    for (int it = 0; it < 2; ++it) {
      ushort vals[8];
      *(float4*)vals = vreg[it];
#pragma unroll
      for (int e = 0; e < 8; ++e) {
        int d = it * 32 + vd0 + e;
        Vt[buf][d * 64 + (vj ^ ((d & 7) << 3))] = vals[e];
      }
    }
  };

  // Q fragments (bf16 source + fp32 u/v), loaded once
  int iq = i0 + 16 * w + low;
  s16x8 qu[2], qv[2];
  {
    const ushort* qrow = qkv + (size_t)(b * L_ + TAU_ + iq) * 3072 + h * 64;
    const float* ur = uvar + h * 64;
    const float* vr = vvar + h * 64;
#pragma unroll
    for (int kc = 0; kc < 2; ++kc) {
      int dbase = kc * 32 + 8 * g;
#pragma unroll
      for (int e = 0; e < 8; ++e) {
        float q = bf2f(qrow[dbase + e]);
        qu[kc][e] = (short)f2bf(q + ur[dbase + e]);
        qv[kc][e] = (short)f2bf(q + vr[dbase + e]);
      }
    }
  }

  f32x4 O[4] = {};
  float mreg[4] = {-INFINITY, -INFINITY, -INFINITY, -INFINITY};
  float lreg[4] = {0.f, 0.f, 0.f, 0.f};

  int ntiles = 9 + bi;       // covers j <= TAU + i0 + 63 exactly
  stage_kr(0, 0);
  vload(0);
  vwrite(0);                 // compiler inserts vmcnt wait on vreg use
  __syncthreads();           // drains DMA + LDS writes: tile 0 ready
  int cur = 0;
  for (int tile = 0; tile < ntiles; ++tile) {
    int j0 = tile * 64;
    bool more = (tile + 1 < ntiles);
    if (more) { stage_kr(cur ^ 1, tile + 1); vload(tile + 1); }

    // ---- QK^T ----
    f32x4 s4[4] = {};
#pragma unroll
    for (int jt = 0; jt < 4; ++jt) {
#pragma unroll
      for (int kc = 0; kc < 2; ++kc) {
        s16x8 kb = *(const s16x8*)&Ks[cur][sw64(jt * 16 + low, kc * 32 + 8 * g)];
        s4[jt] = __builtin_amdgcn_mfma_f32_16x16x32_bf16(qu[kc], kb, s4[jt], 0, 0, 0);
      }
    }
    // ---- P = (q+v)·R over the wave's 80-col m-window ----
    f32x4 p[5] = {};
#pragma unroll
    for (int mt = 0; mt < 5; ++mt) {
#pragma unroll
      for (int kc = 0; kc < 2; ++kc) {
        s16x8 rb = *(const s16x8*)&Rs[cur][sw64(lb_w + mt * 16 + low, kc * 32 + 8 * g)];
        p[mt] = __builtin_amdgcn_mfma_f32_16x16x32_bf16(qv[kc], rb, p[mt], 0, 0, 0);
      }
    }
    // ---- rel-shift via shfl + mask ----
#pragma unroll
    for (int r = 0; r < 4; ++r) {
      int iL = 4 * g + r;
      int src = g * 16 + ((low + 15 - iL) & 15);   // D-layout: col=lane&15
      float sh0 = __shfl(p[0][r], src);
      float sh1 = __shfl(p[1][r], src);
      float sh2 = __shfl(p[2][r], src);
      float sh3 = __shfl(p[3][r], src);
      float sh4 = __shfl(p[4][r], src);
      bool lo = (low <= iL);
      float po0 = lo ? sh0 : sh1;
      float po1 = lo ? sh1 : sh2;
      float po2 = lo ? sh2 : sh3;
      float po3 = lo ? sh3 : sh4;
      int lim = TAU_ + i0 + 16 * w + iL;
      s4[0][r] = (j0 +  0 + low <= lim) ? (s4[0][r] + po0) * 0.125f : -1e30f;
      s4[1][r] = (j0 + 16 + low <= lim) ? (s4[1][r] + po1) * 0.125f : -1e30f;
      s4[2][r] = (j0 + 32 + low <= lim) ? (s4[2][r] + po2) * 0.125f : -1e30f;
      s4[3][r] = (j0 + 48 + low <= lim) ? (s4[3][r] + po3) * 0.125f : -1e30f;
    }
    // ---- online softmax ----
#pragma unroll
    for (int r = 0; r < 4; ++r) {
      float mx = fmaxf(fmaxf(s4[0][r], s4[1][r]), fmaxf(s4[2][r], s4[3][r]));
      mx = fmaxf(mx, __shfl_xor(mx, 1));
      mx = fmaxf(mx, __shfl_xor(mx, 2));
      mx = fmaxf(mx, __shfl_xor(mx, 4));
      mx = fmaxf(mx, __shfl_xor(mx, 8));
      float mn = fmaxf(mreg[r], mx);
      float alpha = __expf(mreg[r] - mn);
      mreg[r] = mn;
      float sum = 0.f;
#pragma unroll
      for (int jt = 0; jt < 4; ++jt) {
        float pe = __expf(s4[jt][r] - mn);
        s4[jt][r] = pe;
        sum += pe;
      }
      sum += __shfl_xor(sum, 1);
      sum += __shfl_xor(sum, 2);
      sum += __shfl_xor(sum, 4);
      sum += __shfl_xor(sum, 8);
      lreg[r] = lreg[r] * alpha + sum;
      O[0][r] *= alpha; O[1][r] *= alpha; O[2][r] *= alpha; O[3][r] *= alpha;
    }
    // ---- P -> bf16 LDS (C-layout -> A-layout transpose) ----
#pragma unroll
    for (int jt = 0; jt < 4; ++jt)
#pragma unroll
      for (int r = 0; r < 4; ++r)
        Pp[w][sw64(4 * g + r, jt * 16 + low)] = f2bf(s4[jt][r]);
    asm volatile("s_waitcnt lgkmcnt(0)" ::: "memory");
    s16x8 pa0 = *(const s16x8*)&Pp[w][sw64(low, 8 * g)];
    s16x8 pa1 = *(const s16x8*)&Pp[w][sw64(low, 32 + 8 * g)];
    // ---- PV ----
#pragma unroll
    for (int dt = 0; dt < 4; ++dt) {
      s16x8 v0 = *(const s16x8*)&Vt[cur][sw64(dt * 16 + low, 8 * g)];
      s16x8 v1 = *(const s16x8*)&Vt[cur][sw64(dt * 16 + low, 32 + 8 * g)];
      O[dt] = __builtin_amdgcn_mfma_f32_16x16x32_bf16(pa0, v0, O[dt], 0, 0, 0);
      O[dt] = __builtin_amdgcn_mfma_f32_16x16x32_bf16(pa1, v1, O[dt], 0, 0, 0);
    }
    if (more) vwrite(cur ^ 1);   // V transpose-write for next tile (late)
    __syncthreads();             // LDS reads done + DMA landed + V writes vis
    cur ^= 1;
  }
  // epilogue: normalize, store bf16 for the out-GEMM
  float inv[4];
#pragma unroll
  for (int r = 0; r < 4; ++r) inv[r] = 1.0f / lreg[r];
#pragma unroll
  for (int dt = 0; dt < 4; ++dt)
#pragma unroll
    for (int r = 0; r < 4; ++r)
      attn[((size_t)(b * T_ + i0 + 16 * w + 4 * g + r)) * 1024 +
           h * 64 + dt * 16 + low] = f2bf(O[dt][r] * inv[r]);
}

// ---------------------------------------------------------------------------
extern "C" void kernel_launch(void* const* d_in, const int* in_sizes, int n_in,
                              void* d_out, int out_size, void* d_ws, size_t ws_size,
                              hipStream_t stream) {
  const float* inputs = (const float*)d_in[0];
  const float* memory = (const float*)d_in[1];
  const float* w_qkv  = (const float*)d_in[2];
  const float* w_pos  = (const float*)d_in[3];
  const float* w_out  = (const float*)d_in[4];
  const float* uvar   = (const float*)d_in[5];
  const float* vvar   = (const float*)d_in[6];
  const float* gamma  = (const float*)d_in[7];
  const float* beta   = (const float*)d_in[8];
  float* out = (float*)d_out;

  // workspace layout, all bf16 (48.2 MB)
  ushort* qkvB = (ushort*)d_ws;                       // 4096*3072
  ushort* xnb  = qkvB + (size_t)4096 * 3072;          // 4096*1024
  ushort* phib = xnb  + (size_t)4096 * 1024;          // 1024*1024
  ushort* RmB  = phib + (size_t)1024 * 1024;          // 1024*1024
  ushort* wqb  = RmB  + (size_t)1024 * 1024;          // 3072*1024
  ushort* wpb  = wqb  + (size_t)3072 * 1024;          // 1024*1024
  ushort* wob  = wpb  + (size_t)1024 * 1024;          // 1024*1024
  ushort* attnb = xnb;                                // reuse after QKV GEMM

  prep_kernel<<<3328, 256, 0, stream>>>(inputs, memory, gamma, beta, xnb,
                                        phib, w_qkv, wqb, w_pos, wpb, w_out, wob);
  qkv_r_gemm<<<1408, 256, 0, stream>>>(xnb, wqb, qkvB, phib, wpb, RmB);
  attn_mfma_kernel<<<dim3(B_ * H_ * 8), 256, 0, stream>>>(qkvB, RmB, uvar, vvar, attnb);
  out_gemm<<<256, 256, 0, stream>>>(attnb, wob, out);
}